// Round 1
// baseline (20.442 us; speedup 1.0000x reference)
//
#include <hip/hip_runtime.h>

// Separable 5x5 median (median of row-medians), zero-padded, f32.
// Each thread: one column w, one strip of TH=8 output rows, rolling
// register window of 5 row-medians.

#define CE(a, b) { float _t = fminf(a, b); (b) = fmaxf(a, b); (a) = _t; }

// exact 3rd-smallest of 5 (no NaNs in input): 5 compare-exchanges + clamp
__device__ __forceinline__ float med5(float a0, float a1, float a2, float a3, float a4) {
    CE(a0, a1); CE(a2, a3); CE(a0, a2); CE(a1, a3); CE(a1, a2);
    // a1 = 2nd smallest of first four, a2 = 3rd smallest of first four
    return fmaxf(a1, fminf(a4, a2));
}

__global__ __launch_bounds__(256) void median5_kernel(const float* __restrict__ in,
                                                      float* __restrict__ out) {
    constexpr int W = 512, H = 512, TH = 8;
    int idx = blockIdx.x * blockDim.x + threadIdx.x;
    int w     = idx & (W - 1);        // column
    int strip = (idx >> 9) & 63;      // H / TH = 64 strips
    int bc    = idx >> 15;            // batch*channel plane
    if (bc >= 24) return;

    const float* p = in  + (size_t)bc * H * W;
    float*       q = out + (size_t)bc * H * W;
    const int h0 = strip * TH;

    auto rowmed = [&](int ih) -> float {
        if (ih < 0 || ih >= H) return 0.0f;   // zero-pad rows -> all-zero window
        const float* r = p + ih * W;
        float a = (w >= 2)     ? r[w - 2] : 0.0f;
        float b = (w >= 1)     ? r[w - 1] : 0.0f;
        float c = r[w];
        float d = (w <= W - 2) ? r[w + 1] : 0.0f;
        float e = (w <= W - 3) ? r[w + 2] : 0.0f;
        return med5(a, b, c, d, e);
    };

    float m0 = rowmed(h0 - 2);
    float m1 = rowmed(h0 - 1);
    float m2 = rowmed(h0);
    float m3 = rowmed(h0 + 1);

    #pragma unroll
    for (int i = 0; i < TH; ++i) {
        int h = h0 + i;
        float m4  = rowmed(h + 2);
        float med = med5(m0, m1, m2, m3, m4);
        float img = p[h * W + w];
        q[h * W + w] = (med - img) + img;   // mirror reference's straight-through expr
        m0 = m1; m1 = m2; m2 = m3; m3 = m4;
    }
}

extern "C" void kernel_launch(void* const* d_in, const int* in_sizes, int n_in,
                              void* d_out, int out_size, void* d_ws, size_t ws_size,
                              hipStream_t stream) {
    const float* in = (const float*)d_in[0];   // [8,3,512,512] f32
    float* out = (float*)d_out;                // same shape, f32
    // kernel_size fixed at 5 by setup_inputs (d_in[1])

    constexpr int W = 512, H = 512, TH = 8, BC = 24;
    int total_threads = BC * (H / TH) * W;     // 786432
    int block = 256;
    int grid = (total_threads + block - 1) / block;  // 3072
    median5_kernel<<<grid, block, 0, stream>>>(in, out);
}

// Round 2
// 19.317 us; speedup vs baseline: 1.0582x; 1.0582x over previous
//
#include <hip/hip_runtime.h>

// Separable 5x5 median (median of row-medians), zero-padded, f32.
// Each thread: 4 consecutive columns (float4), strip of TH=8 output rows,
// rolling register window of 5 row-median float4s.

#define CE(a, b) { float _t = fminf(a, b); (b) = fmaxf(a, b); (a) = _t; }

// exact 3rd-smallest of 5 (no NaNs in input): 5 compare-exchanges + clamp
__device__ __forceinline__ float med5(float a0, float a1, float a2, float a3, float a4) {
    CE(a0, a1); CE(a2, a3); CE(a0, a2); CE(a1, a3); CE(a1, a2);
    return fmaxf(a1, fminf(a4, a2));
}

__device__ __forceinline__ float4 med5v(float4 a0, float4 a1, float4 a2, float4 a3, float4 a4) {
    float4 r;
    r.x = med5(a0.x, a1.x, a2.x, a3.x, a4.x);
    r.y = med5(a0.y, a1.y, a2.y, a3.y, a4.y);
    r.z = med5(a0.z, a1.z, a2.z, a3.z, a4.z);
    r.w = med5(a0.w, a1.w, a2.w, a3.w, a4.w);
    return r;
}

__global__ __launch_bounds__(256) void median5_kernel(const float* __restrict__ in,
                                                      float* __restrict__ out) {
    constexpr int W = 512, H = 512, TH = 8;
    int idx = blockIdx.x * blockDim.x + threadIdx.x;
    int cg    = idx & 127;            // column group (4 cols each)
    int strip = (idx >> 7) & 63;      // H / TH = 64 strips
    int bc    = idx >> 13;            // batch*channel plane (0..23 exactly)

    const float* p = in  + (size_t)bc * H * W;
    float*       q = out + (size_t)bc * H * W;
    const int h0 = strip * TH;
    const int w4 = cg * 4;

    const float4 z4 = make_float4(0.f, 0.f, 0.f, 0.f);

    auto rowmed = [&](int ih) -> float4 {
        if (ih < 0 || ih >= H) return z4;     // zero-pad rows -> all-zero medians
        const float* r = p + ih * W;
        float4 C = *(const float4*)(r + w4);
        float4 L = (w4 >= 4)      ? *(const float4*)(r + w4 - 4) : z4;
        float4 R = (w4 + 4 < W)   ? *(const float4*)(r + w4 + 4) : z4;
        float4 m;
        m.x = med5(L.z, L.w, C.x, C.y, C.z);
        m.y = med5(L.w, C.x, C.y, C.z, C.w);
        m.z = med5(C.x, C.y, C.z, C.w, R.x);
        m.w = med5(C.y, C.z, C.w, R.x, R.y);
        return m;
    };

    float4 m0 = rowmed(h0 - 2);
    float4 m1 = rowmed(h0 - 1);
    float4 m2 = rowmed(h0);
    float4 m3 = rowmed(h0 + 1);

    #pragma unroll
    for (int i = 0; i < TH; ++i) {
        int h = h0 + i;
        float4 m4  = rowmed(h + 2);
        float4 med = med5v(m0, m1, m2, m3, m4);
        float4 img = *(const float4*)(p + h * W + w4);
        float4 o;
        o.x = (med.x - img.x) + img.x;   // mirror reference straight-through expr
        o.y = (med.y - img.y) + img.y;
        o.z = (med.z - img.z) + img.z;
        o.w = (med.w - img.w) + img.w;
        *(float4*)(q + h * W + w4) = o;
        m0 = m1; m1 = m2; m2 = m3; m3 = m4;
    }
}

extern "C" void kernel_launch(void* const* d_in, const int* in_sizes, int n_in,
                              void* d_out, int out_size, void* d_ws, size_t ws_size,
                              hipStream_t stream) {
    const float* in = (const float*)d_in[0];   // [8,3,512,512] f32
    float* out = (float*)d_out;
    constexpr int W = 512, H = 512, TH = 8, BC = 24;
    int total_threads = BC * (H / TH) * (W / 4);   // 196608
    int block = 256;
    int grid = total_threads / block;              // 768
    median5_kernel<<<grid, block, 0, stream>>>(in, out);
}

// Round 3
// 15.848 us; speedup vs baseline: 1.2899x; 1.2189x over previous
//
#include <hip/hip_runtime.h>

// Separable 5x5 median (median of row-medians), zero-padded, f32.
// Thread = 4 consecutive columns (float4) x strip of TH=8 rows.
// Horizontal halo via __shfl from neighbor lanes (consecutive lanes =
// consecutive column groups); rolling register windows for both row-medians
// and center pixels (no img reload). Non-temporal stores.

#define CE(a, b) { float _t = fminf(a, b); (b) = fmaxf(a, b); (a) = _t; }

typedef float f32x4 __attribute__((ext_vector_type(4)));

__device__ __forceinline__ float med5(float a0, float a1, float a2, float a3, float a4) {
    CE(a0, a1); CE(a2, a3); CE(a0, a2); CE(a1, a3); CE(a1, a2);
    return fmaxf(a1, fminf(a4, a2));
}

__global__ __launch_bounds__(256) void median5_kernel(const float* __restrict__ in,
                                                      float* __restrict__ out) {
    constexpr int W = 512, H = 512, TH = 8;
    int idx   = blockIdx.x * blockDim.x + threadIdx.x;
    int cg    = idx & 127;            // column group (4 cols each)
    int strip = (idx >> 7) & 63;      // H / TH = 64 strips
    int bc    = idx >> 13;            // plane 0..23

    const float* p = in  + (size_t)bc * H * W;
    float*       q = out + (size_t)bc * H * W;
    const int h0 = strip * TH;
    const int w4 = cg * 4;
    const int lane = threadIdx.x & 63;
    const bool lEdge = (lane == 0);
    const bool rEdge = (lane == 63);
    const float4 z4 = make_float4(0.f, 0.f, 0.f, 0.f);

    // Row-median for row ih; also returns the center float4 via C.
    auto rowload = [&](int ih, float4& C) -> float4 {
        if (ih < 0 || ih >= H) { C = z4; return z4; }
        const float* r = p + ih * W;
        C = *(const float4*)(r + w4);
        float lz = __shfl_up(C.z, 1);    // lane-1's C.z == r[w4-2]
        float lw = __shfl_up(C.w, 1);    // r[w4-1]
        float rx = __shfl_down(C.x, 1);  // lane+1's C.x == r[w4+4]
        float ry = __shfl_down(C.y, 1);  // r[w4+5]
        if (lEdge) {
            if (w4 >= 4) { lz = r[w4 - 2]; lw = r[w4 - 1]; }
            else         { lz = 0.f;       lw = 0.f; }
        }
        if (rEdge) {
            if (w4 + 4 < W) { rx = r[w4 + 4]; ry = r[w4 + 5]; }
            else            { rx = 0.f;       ry = 0.f; }
        }
        float4 m;
        m.x = med5(lz, lw, C.x, C.y, C.z);
        m.y = med5(lw, C.x, C.y, C.z, C.w);
        m.z = med5(C.x, C.y, C.z, C.w, rx);
        m.w = med5(C.y, C.z, C.w, rx, ry);
        return m;
    };

    float4 cT;                         // scratch center (discarded)
    float4 cA, cB, cC;                 // centers for rows h, h+1, h+2
    float4 m0 = rowload(h0 - 2, cT);
    float4 m1 = rowload(h0 - 1, cT);
    float4 m2 = rowload(h0,     cA);
    float4 m3 = rowload(h0 + 1, cB);

    #pragma unroll
    for (int i = 0; i < TH; ++i) {
        int h = h0 + i;
        float4 m4 = rowload(h + 2, cC);
        float4 o;
        o.x = (med5(m0.x, m1.x, m2.x, m3.x, m4.x) - cA.x) + cA.x;
        o.y = (med5(m0.y, m1.y, m2.y, m3.y, m4.y) - cA.y) + cA.y;
        o.z = (med5(m0.z, m1.z, m2.z, m3.z, m4.z) - cA.z) + cA.z;
        o.w = (med5(m0.w, m1.w, m2.w, m3.w, m4.w) - cA.w) + cA.w;
        f32x4 ov = { o.x, o.y, o.z, o.w };
        __builtin_nontemporal_store(ov, (f32x4*)(q + h * W + w4));
        m0 = m1; m1 = m2; m2 = m3; m3 = m4;
        cA = cB; cB = cC;
    }
}

extern "C" void kernel_launch(void* const* d_in, const int* in_sizes, int n_in,
                              void* d_out, int out_size, void* d_ws, size_t ws_size,
                              hipStream_t stream) {
    const float* in = (const float*)d_in[0];   // [8,3,512,512] f32
    float* out = (float*)d_out;
    constexpr int W = 512, H = 512, TH = 8, BC = 24;
    int total_threads = BC * (H / TH) * (W / 4);   // 196608
    int block = 256;
    int grid = total_threads / block;              // 768
    median5_kernel<<<grid, block, 0, stream>>>(in, out);
}